// Round 8
// baseline (217.908 us; speedup 1.0000x reference)
//
#include <hip/hip_runtime.h>
#include <hip/hip_bf16.h>

#define NN 10000     // nodes
#define NE 640000    // edges
#define NG 64        // graphs
#define NF 128       // feature dim (both layers)
#define NC 10        // classes
#define TM 32        // gemm row tile
#define TKC 32       // gemm k chunk
#define NB 250       // dst buckets (40 nodes each)
#define BSZ 40       // nodes per bucket
#define G1 256       // blocks in hist/bucket passes
#define ECHUNK 2500  // edges per block (G1*ECHUNK == NE)

// ---------------- ws layout (bytes) ----------------
// 0        coff  (10001 int)     40016
// 40016    bbase (251 int)       1024
// 41040    dinv  (10000 f32)     40000
// 81040    csrc  (640000 int)    2560000
// 2641040  cw    (640000 f32)    2560000
// 5201040  bufA  (10000*128 f32) 5120000  [bh (256KB) aliases head: dead before gemm1]
// 10321040 bufB  (10000*128 f32) 5120000  [ebuf (2.56MB) aliases head: dead before gath1]
// total ~15.4 MB; zero global atomics -> no pre-zeroing needed

// Wave-uniform detection of int64 vs int32 index buffers. For little-endian
// int64, every odd 32-bit word is the (always-zero here) high half.
__device__ __forceinline__ int detect64(const int* w, long span) {
    int lane = threadIdx.x & 63;
    long e = (long)lane * (span - 1) / 63;
    return (__ballot(w[2 * e + 1] != 0) == 0ULL) ? 1 : 0;
}

__device__ __forceinline__ int ld_idx(const void* p, long i, int is64) {
    return is64 ? (int)((const long long*)p)[i] : ((const int*)p)[i];
}

// Pass A: per-block bucket histogram, stored bucket-major: bh[b*G1 + g].
__global__ __launch_bounds__(256) void k_hist(const void* __restrict__ ei,
                                              int* __restrict__ bh) {
    int is64 = detect64((const int*)ei, NE);
    __shared__ int hist[256];
    int tid = threadIdx.x;
    hist[tid] = 0;
    __syncthreads();
    int e0 = blockIdx.x * ECHUNK, e1 = min(NE, e0 + ECHUNK);
    for (int e = e0 + tid; e < e1; e += 256) {
        int dst = ld_idx(ei, (long)NE + e, is64);
        atomicAdd(&hist[dst / BSZ], 1);
    }
    __syncthreads();
    bh[tid * G1 + blockIdx.x] = hist[tid];
}

// Pass B (single block): per-bucket exclusive prefix over G1 group counts
// (wave-scan, 4 vals/lane), then bucket-base scan -> bbase.
__global__ __launch_bounds__(1024) void k_bscan(int* __restrict__ bh,
                                                int* __restrict__ bbase) {
    __shared__ int btot[256];
    __shared__ int bb[NB + 1];
    int tid = threadIdx.x, wv = tid >> 6, lane = tid & 63;
    for (int b = wv; b < NB; b += 16) {
        int base = b * G1 + lane * 4;
        int vals[4];
        int lsum = 0;
#pragma unroll
        for (int i = 0; i < 4; ++i) { vals[i] = bh[base + i]; lsum += vals[i]; }
        int pref = lsum;
        for (int o = 1; o < 64; o <<= 1) {
            int t = __shfl_up(pref, o, 64);
            if (lane >= o) pref += t;
        }
        int run = pref - lsum;              // exclusive
#pragma unroll
        for (int i = 0; i < 4; ++i) { int v = vals[i]; bh[base + i] = run; run += v; }
        if (lane == 63) btot[b] = run;
    }
    __syncthreads();
    if (tid == 0) {
        int run = 0;
        for (int b = 0; b < NB; ++b) { bb[b] = run; run += btot[b]; }
        bb[NB] = run;                        // == NE
    }
    __syncthreads();
    if (tid <= NB) bbase[tid] = bb[tid];
}

// Pass C: scatter edges to bucket regions, packed (ldst<<14)|src. Each block
// owns a CONTIGUOUS sub-range per bucket (prefix cursors) -> low write amp.
__global__ __launch_bounds__(256) void k_bucket(const void* __restrict__ ei,
                                                const int* __restrict__ bh,
                                                const int* __restrict__ bbase,
                                                int* __restrict__ ebuf) {
    int is64 = detect64((const int*)ei, NE);
    __shared__ int cur[256];
    int tid = threadIdx.x;
    if (tid < NB) cur[tid] = bh[tid * G1 + blockIdx.x] + bbase[tid];
    __syncthreads();
    int e0 = blockIdx.x * ECHUNK, e1 = min(NE, e0 + ECHUNK);
    for (int e = e0 + tid; e < e1; e += 256) {
        int dst = ld_idx(ei, (long)NE + e, is64);
        int src = ld_idx(ei, (long)e, is64);
        int b = dst / BSZ;
        int p = atomicAdd(&cur[b], 1);
        ebuf[p] = ((dst - b * BSZ) << 14) | src;
    }
}

// Pass D: one block per bucket. Count/scan 40 dsts -> coff + dinv; scatter
// csrc within the block-private contiguous region.
__global__ __launch_bounds__(256) void k_csr(const int* __restrict__ ebuf,
                                             const int* __restrict__ bbase,
                                             int* __restrict__ coff,
                                             float* __restrict__ dinv,
                                             int* __restrict__ csrc) {
    __shared__ int dcount[BSZ];
    __shared__ int dstart[BSZ];
    __shared__ int cur[BSZ];
    int b = blockIdx.x, tid = threadIdx.x;
    if (tid < BSZ) dcount[tid] = 0;
    __syncthreads();
    int base = bbase[b], end = bbase[b + 1];
    for (int i = base + tid; i < end; i += 256)
        atomicAdd(&dcount[ebuf[i] >> 14], 1);
    __syncthreads();
    if (tid == 0) {
        int run = 0;
        for (int i = 0; i < BSZ; ++i) {
            dstart[i] = run; cur[i] = base + run; run += dcount[i];
        }
    }
    __syncthreads();
    if (tid < BSZ) {
        coff[b * BSZ + tid] = base + dstart[tid];
        dinv[b * BSZ + tid] = rsqrtf((float)dcount[tid] + 1.0f);
    }
    if (b == NB - 1 && tid == 0) coff[NN] = NE;
    __syncthreads();
    for (int i = base + tid; i < end; i += 256) {
        int pk = ebuf[i];
        int p = atomicAdd(&cur[pk >> 14], 1);
        csrc[p] = pk & 16383;
    }
}

// Pass E: per-node edge weights cw[e] = dinv[src]*dinv[dst] (linear csrc read,
// random 4B dinv reads from a 40KB L1/L2-hot table, linear cw write).
__global__ __launch_bounds__(256) void k_cw(const int* __restrict__ coff,
                                            const int* __restrict__ csrc,
                                            const float* __restrict__ dinv,
                                            float* __restrict__ cw) {
    int n = blockIdx.x * 4 + (threadIdx.x >> 6);
    if (n >= NN) return;
    int lane = threadIdx.x & 63;
    int beg = coff[n], end = coff[n + 1];
    float din = dinv[n];
    for (int e = beg + lane; e < end; e += 64)
        cw[e] = dinv[csrc[e]] * din;
}

// Y = X @ W, register-tiled. Block: 256 thr, 32 rows x 128 cols; 4x4 acc.
__global__ __launch_bounds__(256) void k_gemm(const float* __restrict__ X,
                                              const float* __restrict__ W,
                                              float* __restrict__ Y, int nrows) {
    __shared__ float sX[TKC * 36];       // 4.6 KB
    __shared__ float sW[32 * 132];       // 16.9 KB
    int tid = threadIdx.x;
    int rg = tid & 7;                    // rows rg*4 .. rg*4+3
    int cg = tid >> 3;                   // cols cg*4 .. cg*4+3 (0..31)
    int m0 = blockIdx.x * TM;
    float acc[4][4] = {{0.f}};
    for (int kc = 0; kc < NF / TKC; ++kc) {
        int k0 = kc * TKC;
        {   // stage X^T (one float4 per thread)
            int row = tid >> 3, kq = tid & 7;
            int mm = m0 + row; if (mm > nrows - 1) mm = nrows - 1;
            float4 v = *(const float4*)(X + (size_t)mm * NF + k0 + kq * 4);
            sX[(kq * 4 + 0) * 36 + row] = v.x;
            sX[(kq * 4 + 1) * 36 + row] = v.y;
            sX[(kq * 4 + 2) * 36 + row] = v.z;
            sX[(kq * 4 + 3) * 36 + row] = v.w;
        }
#pragma unroll
        for (int j = 0; j < 4; ++j) {    // stage W panels (4 float4 per thread)
            int idx = tid + 256 * j;
            int k = idx >> 5, cq = idx & 31;
            float4 v = *(const float4*)(W + (size_t)(k0 + k) * NF + cq * 4);
            *(float4*)(sW + cq * 132 + k * 4) = v;
        }
        __syncthreads();
#pragma unroll 8
        for (int k = 0; k < TKC; ++k) {
            float4 xf = *(const float4*)(sX + k * 36 + rg * 4);
            float4 wf = *(const float4*)(sW + cg * 132 + k * 4);
            acc[0][0] = fmaf(xf.x, wf.x, acc[0][0]);
            acc[0][1] = fmaf(xf.x, wf.y, acc[0][1]);
            acc[0][2] = fmaf(xf.x, wf.z, acc[0][2]);
            acc[0][3] = fmaf(xf.x, wf.w, acc[0][3]);
            acc[1][0] = fmaf(xf.y, wf.x, acc[1][0]);
            acc[1][1] = fmaf(xf.y, wf.y, acc[1][1]);
            acc[1][2] = fmaf(xf.y, wf.z, acc[1][2]);
            acc[1][3] = fmaf(xf.y, wf.w, acc[1][3]);
            acc[2][0] = fmaf(xf.z, wf.x, acc[2][0]);
            acc[2][1] = fmaf(xf.z, wf.y, acc[2][1]);
            acc[2][2] = fmaf(xf.z, wf.z, acc[2][2]);
            acc[2][3] = fmaf(xf.z, wf.w, acc[2][3]);
            acc[3][0] = fmaf(xf.w, wf.x, acc[3][0]);
            acc[3][1] = fmaf(xf.w, wf.y, acc[3][1]);
            acc[3][2] = fmaf(xf.w, wf.z, acc[3][2]);
            acc[3][3] = fmaf(xf.w, wf.w, acc[3][3]);
        }
        __syncthreads();
    }
#pragma unroll
    for (int r = 0; r < 4; ++r) {
        int m = m0 + rg * 4 + r;
        if (m < nrows)
            *(float4*)(Y + (size_t)m * NF + cg * 4) =
                make_float4(acc[r][0], acc[r][1], acc[r][2], acc[r][3]);
    }
}

// Feature-half gather: processes 64 of 128 features (hoff = 0 or 64) so the
// random-row working set (2.56MB) fits a 4MB per-XCD L2 (full 5.1MB doesn't;
// R7 gather ran at ~9.3TB/s = L3 ceiling). One wave per node; quarter-wave
// (16 lanes x float4 = 256B) per edge; 4-deep unroll -> 16 rows in flight.
__global__ __launch_bounds__(256) void k_gath(const float* __restrict__ XW,
                                              const int* __restrict__ off,
                                              const int* __restrict__ csrc,
                                              const float* __restrict__ cw,
                                              const float* __restrict__ dinv,
                                              const float* __restrict__ bias,
                                              float* __restrict__ OUT, int hoff) {
    int wid = threadIdx.x >> 6, lane = threadIdx.x & 63;
    int q = lane >> 4, f = lane & 15;
    int n = blockIdx.x * 4 + wid;
    if (n >= NN) return;
    int beg = off[n], end = off[n + 1];
    float din = dinv[n];
    const float* base = XW + hoff;
    float4 acc = make_float4(0.f, 0.f, 0.f, 0.f);
    int e = beg + q;
    for (; e + 12 < end; e += 16) {
        int s0 = csrc[e],     s1 = csrc[e + 4];
        int s2 = csrc[e + 8], s3 = csrc[e + 12];
        float w0 = cw[e],     w1 = cw[e + 4];
        float w2 = cw[e + 8], w3 = cw[e + 12];
        float4 v0 = ((const float4*)(base + (size_t)s0 * NF))[f];
        float4 v1 = ((const float4*)(base + (size_t)s1 * NF))[f];
        float4 v2 = ((const float4*)(base + (size_t)s2 * NF))[f];
        float4 v3 = ((const float4*)(base + (size_t)s3 * NF))[f];
        acc.x = fmaf(v0.x, w0, acc.x); acc.y = fmaf(v0.y, w0, acc.y);
        acc.z = fmaf(v0.z, w0, acc.z); acc.w = fmaf(v0.w, w0, acc.w);
        acc.x = fmaf(v1.x, w1, acc.x); acc.y = fmaf(v1.y, w1, acc.y);
        acc.z = fmaf(v1.z, w1, acc.z); acc.w = fmaf(v1.w, w1, acc.w);
        acc.x = fmaf(v2.x, w2, acc.x); acc.y = fmaf(v2.y, w2, acc.y);
        acc.z = fmaf(v2.z, w2, acc.z); acc.w = fmaf(v2.w, w2, acc.w);
        acc.x = fmaf(v3.x, w3, acc.x); acc.y = fmaf(v3.y, w3, acc.y);
        acc.z = fmaf(v3.z, w3, acc.z); acc.w = fmaf(v3.w, w3, acc.w);
    }
    for (; e < end; e += 4) {
        int s = csrc[e];
        float w = cw[e];
        float4 v = ((const float4*)(base + (size_t)s * NF))[f];
        acc.x = fmaf(v.x, w, acc.x); acc.y = fmaf(v.y, w, acc.y);
        acc.z = fmaf(v.z, w, acc.z); acc.w = fmaf(v.w, w, acc.w);
    }
    acc.x += __shfl_xor(acc.x, 16); acc.y += __shfl_xor(acc.y, 16);
    acc.z += __shfl_xor(acc.z, 16); acc.w += __shfl_xor(acc.w, 16);
    acc.x += __shfl_xor(acc.x, 32); acc.y += __shfl_xor(acc.y, 32);
    acc.z += __shfl_xor(acc.z, 32); acc.w += __shfl_xor(acc.w, 32);
    if (lane < 16) {
        float4 sv = ((const float4*)(base + (size_t)n * NF))[f];
        float4 bb = ((const float4*)(bias + hoff))[f];
        float d2 = din * din;
        float4 o;
        o.x = fmaxf(fmaf(sv.x, d2, acc.x) + bb.x, 0.f);
        o.y = fmaxf(fmaf(sv.y, d2, acc.y) + bb.y, 0.f);
        o.z = fmaxf(fmaf(sv.z, d2, acc.z) + bb.z, 0.f);
        o.w = fmaxf(fmaf(sv.w, d2, acc.w) + bb.w, 0.f);
        ((float4*)(OUT + (size_t)n * NF + hoff))[f] = o;
    }
}

// Fused global-mean-pool + final linear (batch is sorted -> contiguous ranges).
__global__ __launch_bounds__(256) void k_poolfin(const float* __restrict__ H,
                                                 const void* __restrict__ batch,
                                                 const float* __restrict__ Wl,
                                                 const float* __restrict__ bl,
                                                 float* __restrict__ out) {
    int is64 = detect64((const int*)batch, NN / 2);
    __shared__ int sb[2];
    __shared__ float4 part[256];
    __shared__ float pooled[NF];
    int g = blockIdx.x;
    int tid = threadIdx.x;
    if (tid < 2) {
        int target = g + tid;                 // lower_bound(batch, target)
        int lo = 0, hi = NN;
        while (lo < hi) {
            int mid = (lo + hi) >> 1;
            if (ld_idx(batch, mid, is64) < target) lo = mid + 1; else hi = mid;
        }
        sb[tid] = lo;
    }
    __syncthreads();
    int beg = sb[0], end = sb[1];
    int c4 = tid & 31, r = tid >> 5;          // 8 rows in flight
    float4 acc = make_float4(0.f, 0.f, 0.f, 0.f);
    for (int n = beg + r; n < end; n += 8) {
        float4 v = ((const float4*)(H + (size_t)n * NF))[c4];
        acc.x += v.x; acc.y += v.y; acc.z += v.z; acc.w += v.w;
    }
    part[tid] = acc;
    __syncthreads();
    if (tid < 32) {
        float4 s = part[tid];
#pragma unroll
        for (int j = 1; j < 8; j++) {
            float4 p = part[tid + 32 * j];
            s.x += p.x; s.y += p.y; s.z += p.z; s.w += p.w;
        }
        float ic = 1.0f / fmaxf((float)(end - beg), 1.0f);
        pooled[tid * 4 + 0] = s.x * ic;
        pooled[tid * 4 + 1] = s.y * ic;
        pooled[tid * 4 + 2] = s.z * ic;
        pooled[tid * 4 + 3] = s.w * ic;
    }
    __syncthreads();
    if (tid < NC) {
        float a = bl[tid];
#pragma unroll 8
        for (int k = 0; k < NF; k++)
            a = fmaf(pooled[k], Wl[k * NC + tid], a);
        out[g * NC + tid] = a;
    }
}

extern "C" void kernel_launch(void* const* d_in, const int* in_sizes, int n_in,
                              void* d_out, int out_size, void* d_ws, size_t ws_size,
                              hipStream_t stream) {
    const float* x  = (const float*)d_in[0];
    const void*  ei = d_in[1];
    const void*  bt = d_in[2];
    const float* W1 = (const float*)d_in[3];
    const float* b1 = (const float*)d_in[4];
    const float* W2 = (const float*)d_in[5];
    const float* b2 = (const float*)d_in[6];
    const float* Wl = (const float*)d_in[7];
    const float* bl = (const float*)d_in[8];

    char* ws = (char*)d_ws;
    int*   coff  = (int*)(ws + 0);
    int*   bbase = (int*)(ws + 40016);
    float* dinv  = (float*)(ws + 41040);
    int*   csrc  = (int*)(ws + 81040);
    float* cw    = (float*)(ws + 2641040);
    float* bufA  = (float*)(ws + 5201040);
    float* bufB  = (float*)(ws + 10321040);
    int*   bh    = (int*)bufA;     // 256 KB scratch, dead before k_gemm #1
    int*   ebuf  = (int*)bufB;     // 2.56 MB scratch, dead before k_gath #1

    k_hist  <<<G1, 256, 0, stream>>>(ei, bh);
    k_bscan <<<1, 1024, 0, stream>>>(bh, bbase);
    k_bucket<<<G1, 256, 0, stream>>>(ei, bh, bbase, ebuf);
    k_csr   <<<NB, 256, 0, stream>>>(ebuf, bbase, coff, dinv, csrc);
    k_cw    <<<(NN + 3) / 4, 256, 0, stream>>>(coff, csrc, dinv, cw);

    k_gemm<<<(NN + TM - 1) / TM, 256, 0, stream>>>(x, W1, bufA, NN);
    k_gath<<<(NN + 3) / 4, 256, 0, stream>>>(bufA, coff, csrc, cw, dinv, b1, bufB, 0);
    k_gath<<<(NN + 3) / 4, 256, 0, stream>>>(bufA, coff, csrc, cw, dinv, b1, bufB, 64);
    k_gemm<<<(NN + TM - 1) / TM, 256, 0, stream>>>(bufB, W2, bufA, NN);
    k_gath<<<(NN + 3) / 4, 256, 0, stream>>>(bufA, coff, csrc, cw, dinv, b2, bufB, 0);
    k_gath<<<(NN + 3) / 4, 256, 0, stream>>>(bufA, coff, csrc, cw, dinv, b2, bufB, 64);

    k_poolfin<<<NG, 256, 0, stream>>>(bufB, bt, Wl, bl, (float*)d_out);
}

// Round 9
// 209.079 us; speedup vs baseline: 1.0422x; 1.0422x over previous
//
#include <hip/hip_runtime.h>
#include <hip/hip_bf16.h>

#define NN 10000     // nodes
#define NE 640000    // edges
#define NG 64        // graphs
#define NF 128       // feature dim (both layers)
#define NC 10        // classes
#define TM 32        // gemm row tile
#define TKC 32       // gemm k chunk
#define NB 250       // dst buckets (40 nodes each)
#define BSZ 40       // nodes per bucket
#define G1 256       // blocks in hist/bucket passes
#define ECHUNK 2500  // edges per block (G1*ECHUNK == NE)

// ---------------- ws layout (bytes) ----------------
// 0        coff  (10001 int)     40016
// 40016    bbase (251 int)       1024
// 41040    dinv  (10000 f32)     40000
// 81040    csrc  (640000 int)    2560000
// 2641040  cw    (640000 f32)    2560000
// 5201040  bufA  (10000*128 f32) 5120000  [bh (256KB) aliases head: dead before gemm1]
// 10321040 bufB  (10000*128 f32) 5120000  [ebuf (2.56MB) aliases head: dead before gath1]
// total ~15.4 MB; zero global atomics -> no pre-zeroing needed

// Wave-uniform detection of int64 vs int32 index buffers. For little-endian
// int64, every odd 32-bit word is the (always-zero here) high half.
__device__ __forceinline__ int detect64(const int* w, long span) {
    int lane = threadIdx.x & 63;
    long e = (long)lane * (span - 1) / 63;
    return (__ballot(w[2 * e + 1] != 0) == 0ULL) ? 1 : 0;
}

__device__ __forceinline__ int ld_idx(const void* p, long i, int is64) {
    return is64 ? (int)((const long long*)p)[i] : ((const int*)p)[i];
}

// Pass A: per-block bucket histogram, stored bucket-major: bh[b*G1 + g].
__global__ __launch_bounds__(256) void k_hist(const void* __restrict__ ei,
                                              int* __restrict__ bh) {
    int is64 = detect64((const int*)ei, NE);
    __shared__ int hist[256];
    int tid = threadIdx.x;
    hist[tid] = 0;
    __syncthreads();
    int e0 = blockIdx.x * ECHUNK, e1 = min(NE, e0 + ECHUNK);
    for (int e = e0 + tid; e < e1; e += 256) {
        int dst = ld_idx(ei, (long)NE + e, is64);
        atomicAdd(&hist[dst / BSZ], 1);
    }
    __syncthreads();
    bh[tid * G1 + blockIdx.x] = hist[tid];
}

// Pass B (single block): per-bucket exclusive prefix over G1 group counts
// (wave-scan, 4 vals/lane), then bucket-base scan -> bbase.
__global__ __launch_bounds__(1024) void k_bscan(int* __restrict__ bh,
                                                int* __restrict__ bbase) {
    __shared__ int btot[256];
    __shared__ int bb[NB + 1];
    int tid = threadIdx.x, wv = tid >> 6, lane = tid & 63;
    for (int b = wv; b < NB; b += 16) {
        int base = b * G1 + lane * 4;
        int vals[4];
        int lsum = 0;
#pragma unroll
        for (int i = 0; i < 4; ++i) { vals[i] = bh[base + i]; lsum += vals[i]; }
        int pref = lsum;
        for (int o = 1; o < 64; o <<= 1) {
            int t = __shfl_up(pref, o, 64);
            if (lane >= o) pref += t;
        }
        int run = pref - lsum;              // exclusive
#pragma unroll
        for (int i = 0; i < 4; ++i) { int v = vals[i]; bh[base + i] = run; run += v; }
        if (lane == 63) btot[b] = run;
    }
    __syncthreads();
    if (tid == 0) {
        int run = 0;
        for (int b = 0; b < NB; ++b) { bb[b] = run; run += btot[b]; }
        bb[NB] = run;                        // == NE
    }
    __syncthreads();
    if (tid <= NB) bbase[tid] = bb[tid];
}

// Pass C: scatter edges to bucket regions, packed (ldst<<14)|src. Each block
// owns a CONTIGUOUS sub-range per bucket (prefix cursors) -> low write amp.
__global__ __launch_bounds__(256) void k_bucket(const void* __restrict__ ei,
                                                const int* __restrict__ bh,
                                                const int* __restrict__ bbase,
                                                int* __restrict__ ebuf) {
    int is64 = detect64((const int*)ei, NE);
    __shared__ int cur[256];
    int tid = threadIdx.x;
    if (tid < NB) cur[tid] = bh[tid * G1 + blockIdx.x] + bbase[tid];
    __syncthreads();
    int e0 = blockIdx.x * ECHUNK, e1 = min(NE, e0 + ECHUNK);
    for (int e = e0 + tid; e < e1; e += 256) {
        int dst = ld_idx(ei, (long)NE + e, is64);
        int src = ld_idx(ei, (long)e, is64);
        int b = dst / BSZ;
        int p = atomicAdd(&cur[b], 1);
        ebuf[p] = ((dst - b * BSZ) << 14) | src;
    }
}

// Pass D: one block per bucket. Count/scan 40 dsts -> coff + dinv; scatter
// csrc within the block-private contiguous region.
__global__ __launch_bounds__(256) void k_csr(const int* __restrict__ ebuf,
                                             const int* __restrict__ bbase,
                                             int* __restrict__ coff,
                                             float* __restrict__ dinv,
                                             int* __restrict__ csrc) {
    __shared__ int dcount[BSZ];
    __shared__ int dstart[BSZ];
    __shared__ int cur[BSZ];
    int b = blockIdx.x, tid = threadIdx.x;
    if (tid < BSZ) dcount[tid] = 0;
    __syncthreads();
    int base = bbase[b], end = bbase[b + 1];
    for (int i = base + tid; i < end; i += 256)
        atomicAdd(&dcount[ebuf[i] >> 14], 1);
    __syncthreads();
    if (tid == 0) {
        int run = 0;
        for (int i = 0; i < BSZ; ++i) {
            dstart[i] = run; cur[i] = base + run; run += dcount[i];
        }
    }
    __syncthreads();
    if (tid < BSZ) {
        coff[b * BSZ + tid] = base + dstart[tid];
        dinv[b * BSZ + tid] = rsqrtf((float)dcount[tid] + 1.0f);
    }
    if (b == NB - 1 && tid == 0) coff[NN] = NE;
    __syncthreads();
    for (int i = base + tid; i < end; i += 256) {
        int pk = ebuf[i];
        int p = atomicAdd(&cur[pk >> 14], 1);
        csrc[p] = pk & 16383;
    }
}

// Pass E: per-node edge weights cw[e] = dinv[src]*dinv[dst] (linear csrc read,
// random 4B dinv reads from a 40KB L1/L2-hot table, linear cw write).
__global__ __launch_bounds__(256) void k_cw(const int* __restrict__ coff,
                                            const int* __restrict__ csrc,
                                            const float* __restrict__ dinv,
                                            float* __restrict__ cw) {
    int n = blockIdx.x * 4 + (threadIdx.x >> 6);
    if (n >= NN) return;
    int lane = threadIdx.x & 63;
    int beg = coff[n], end = coff[n + 1];
    float din = dinv[n];
    for (int e = beg + lane; e < end; e += 64)
        cw[e] = dinv[csrc[e]] * din;
}

// Y = X @ W, register-tiled. Block: 256 thr, 32 rows x 128 cols; 4x4 acc.
__global__ __launch_bounds__(256) void k_gemm(const float* __restrict__ X,
                                              const float* __restrict__ W,
                                              float* __restrict__ Y, int nrows) {
    __shared__ float sX[TKC * 36];       // 4.6 KB
    __shared__ float sW[32 * 132];       // 16.9 KB
    int tid = threadIdx.x;
    int rg = tid & 7;                    // rows rg*4 .. rg*4+3
    int cg = tid >> 3;                   // cols cg*4 .. cg*4+3 (0..31)
    int m0 = blockIdx.x * TM;
    float acc[4][4] = {{0.f}};
    for (int kc = 0; kc < NF / TKC; ++kc) {
        int k0 = kc * TKC;
        {   // stage X^T (one float4 per thread)
            int row = tid >> 3, kq = tid & 7;
            int mm = m0 + row; if (mm > nrows - 1) mm = nrows - 1;
            float4 v = *(const float4*)(X + (size_t)mm * NF + k0 + kq * 4);
            sX[(kq * 4 + 0) * 36 + row] = v.x;
            sX[(kq * 4 + 1) * 36 + row] = v.y;
            sX[(kq * 4 + 2) * 36 + row] = v.z;
            sX[(kq * 4 + 3) * 36 + row] = v.w;
        }
#pragma unroll
        for (int j = 0; j < 4; ++j) {    // stage W panels (4 float4 per thread)
            int idx = tid + 256 * j;
            int k = idx >> 5, cq = idx & 31;
            float4 v = *(const float4*)(W + (size_t)(k0 + k) * NF + cq * 4);
            *(float4*)(sW + cq * 132 + k * 4) = v;
        }
        __syncthreads();
#pragma unroll 8
        for (int k = 0; k < TKC; ++k) {
            float4 xf = *(const float4*)(sX + k * 36 + rg * 4);
            float4 wf = *(const float4*)(sW + cg * 132 + k * 4);
            acc[0][0] = fmaf(xf.x, wf.x, acc[0][0]);
            acc[0][1] = fmaf(xf.x, wf.y, acc[0][1]);
            acc[0][2] = fmaf(xf.x, wf.z, acc[0][2]);
            acc[0][3] = fmaf(xf.x, wf.w, acc[0][3]);
            acc[1][0] = fmaf(xf.y, wf.x, acc[1][0]);
            acc[1][1] = fmaf(xf.y, wf.y, acc[1][1]);
            acc[1][2] = fmaf(xf.y, wf.z, acc[1][2]);
            acc[1][3] = fmaf(xf.y, wf.w, acc[1][3]);
            acc[2][0] = fmaf(xf.z, wf.x, acc[2][0]);
            acc[2][1] = fmaf(xf.z, wf.y, acc[2][1]);
            acc[2][2] = fmaf(xf.z, wf.z, acc[2][2]);
            acc[2][3] = fmaf(xf.z, wf.w, acc[2][3]);
            acc[3][0] = fmaf(xf.w, wf.x, acc[3][0]);
            acc[3][1] = fmaf(xf.w, wf.y, acc[3][1]);
            acc[3][2] = fmaf(xf.w, wf.z, acc[3][2]);
            acc[3][3] = fmaf(xf.w, wf.w, acc[3][3]);
        }
        __syncthreads();
    }
#pragma unroll
    for (int r = 0; r < 4; ++r) {
        int m = m0 + rg * 4 + r;
        if (m < nrows)
            *(float4*)(Y + (size_t)m * NF + cg * 4) =
                make_float4(acc[r][0], acc[r][1], acc[r][2], acc[r][3]);
    }
}

// OUT[n] = relu( sum_e cw[e]*XW[csrc[e]] + XW[n]*dinv[n]^2 + bias )
// One wave per node; half-wave (32 lanes x float4 = 512B) per edge; 8-deep
// unroll -> 16 independent row reads in flight per wave (latency-bound
// gather: R8 showed working-set shaping doesn't help; MLP depth does).
__global__ __launch_bounds__(256) void k_gather(const float* __restrict__ XW,
                                                const int* __restrict__ off,
                                                const int* __restrict__ csrc,
                                                const float* __restrict__ cw,
                                                const float* __restrict__ dinv,
                                                const float* __restrict__ bias,
                                                float* __restrict__ OUT) {
    int wid = threadIdx.x >> 6, lane = threadIdx.x & 63;
    int half = lane >> 5;
    int c4 = lane & 31;
    int n = blockIdx.x * 4 + wid;
    if (n >= NN) return;
    int beg = off[n], end = off[n + 1];
    float din = dinv[n];
    float4 acc = make_float4(0.f, 0.f, 0.f, 0.f);
    int e = beg + half;
    for (; e + 14 < end; e += 16) {
        int s0 = csrc[e],      s1 = csrc[e + 2];
        int s2 = csrc[e + 4],  s3 = csrc[e + 6];
        int s4 = csrc[e + 8],  s5 = csrc[e + 10];
        int s6 = csrc[e + 12], s7 = csrc[e + 14];
        float w0 = cw[e],      w1 = cw[e + 2];
        float w2 = cw[e + 4],  w3 = cw[e + 6];
        float w4 = cw[e + 8],  w5 = cw[e + 10];
        float w6 = cw[e + 12], w7 = cw[e + 14];
        float4 v0 = ((const float4*)(XW + (size_t)s0 * NF))[c4];
        float4 v1 = ((const float4*)(XW + (size_t)s1 * NF))[c4];
        float4 v2 = ((const float4*)(XW + (size_t)s2 * NF))[c4];
        float4 v3 = ((const float4*)(XW + (size_t)s3 * NF))[c4];
        float4 v4 = ((const float4*)(XW + (size_t)s4 * NF))[c4];
        float4 v5 = ((const float4*)(XW + (size_t)s5 * NF))[c4];
        float4 v6 = ((const float4*)(XW + (size_t)s6 * NF))[c4];
        float4 v7 = ((const float4*)(XW + (size_t)s7 * NF))[c4];
        acc.x = fmaf(v0.x, w0, acc.x); acc.y = fmaf(v0.y, w0, acc.y);
        acc.z = fmaf(v0.z, w0, acc.z); acc.w = fmaf(v0.w, w0, acc.w);
        acc.x = fmaf(v1.x, w1, acc.x); acc.y = fmaf(v1.y, w1, acc.y);
        acc.z = fmaf(v1.z, w1, acc.z); acc.w = fmaf(v1.w, w1, acc.w);
        acc.x = fmaf(v2.x, w2, acc.x); acc.y = fmaf(v2.y, w2, acc.y);
        acc.z = fmaf(v2.z, w2, acc.z); acc.w = fmaf(v2.w, w2, acc.w);
        acc.x = fmaf(v3.x, w3, acc.x); acc.y = fmaf(v3.y, w3, acc.y);
        acc.z = fmaf(v3.z, w3, acc.z); acc.w = fmaf(v3.w, w3, acc.w);
        acc.x = fmaf(v4.x, w4, acc.x); acc.y = fmaf(v4.y, w4, acc.y);
        acc.z = fmaf(v4.z, w4, acc.z); acc.w = fmaf(v4.w, w4, acc.w);
        acc.x = fmaf(v5.x, w5, acc.x); acc.y = fmaf(v5.y, w5, acc.y);
        acc.z = fmaf(v5.z, w5, acc.z); acc.w = fmaf(v5.w, w5, acc.w);
        acc.x = fmaf(v6.x, w6, acc.x); acc.y = fmaf(v6.y, w6, acc.y);
        acc.z = fmaf(v6.z, w6, acc.z); acc.w = fmaf(v6.w, w6, acc.w);
        acc.x = fmaf(v7.x, w7, acc.x); acc.y = fmaf(v7.y, w7, acc.y);
        acc.z = fmaf(v7.z, w7, acc.z); acc.w = fmaf(v7.w, w7, acc.w);
    }
    for (; e < end; e += 2) {
        int s = csrc[e];
        float w = cw[e];
        float4 v = ((const float4*)(XW + (size_t)s * NF))[c4];
        acc.x = fmaf(v.x, w, acc.x); acc.y = fmaf(v.y, w, acc.y);
        acc.z = fmaf(v.z, w, acc.z); acc.w = fmaf(v.w, w, acc.w);
    }
    acc.x += __shfl_xor(acc.x, 32);
    acc.y += __shfl_xor(acc.y, 32);
    acc.z += __shfl_xor(acc.z, 32);
    acc.w += __shfl_xor(acc.w, 32);
    if (half == 0) {
        float4 sv = ((const float4*)(XW + (size_t)n * NF))[c4];
        float4 bb = ((const float4*)bias)[c4];
        float d2 = din * din;
        float4 o;
        o.x = fmaxf(fmaf(sv.x, d2, acc.x) + bb.x, 0.f);
        o.y = fmaxf(fmaf(sv.y, d2, acc.y) + bb.y, 0.f);
        o.z = fmaxf(fmaf(sv.z, d2, acc.z) + bb.z, 0.f);
        o.w = fmaxf(fmaf(sv.w, d2, acc.w) + bb.w, 0.f);
        ((float4*)(OUT + (size_t)n * NF))[c4] = o;
    }
}

// Fused global-mean-pool + final linear (batch is sorted -> contiguous ranges).
__global__ __launch_bounds__(256) void k_poolfin(const float* __restrict__ H,
                                                 const void* __restrict__ batch,
                                                 const float* __restrict__ Wl,
                                                 const float* __restrict__ bl,
                                                 float* __restrict__ out) {
    int is64 = detect64((const int*)batch, NN / 2);
    __shared__ int sb[2];
    __shared__ float4 part[256];
    __shared__ float pooled[NF];
    int g = blockIdx.x;
    int tid = threadIdx.x;
    if (tid < 2) {
        int target = g + tid;                 // lower_bound(batch, target)
        int lo = 0, hi = NN;
        while (lo < hi) {
            int mid = (lo + hi) >> 1;
            if (ld_idx(batch, mid, is64) < target) lo = mid + 1; else hi = mid;
        }
        sb[tid] = lo;
    }
    __syncthreads();
    int beg = sb[0], end = sb[1];
    int c4 = tid & 31, r = tid >> 5;          // 8 rows in flight
    float4 acc = make_float4(0.f, 0.f, 0.f, 0.f);
    for (int n = beg + r; n < end; n += 8) {
        float4 v = ((const float4*)(H + (size_t)n * NF))[c4];
        acc.x += v.x; acc.y += v.y; acc.z += v.z; acc.w += v.w;
    }
    part[tid] = acc;
    __syncthreads();
    if (tid < 32) {
        float4 s = part[tid];
#pragma unroll
        for (int j = 1; j < 8; j++) {
            float4 p = part[tid + 32 * j];
            s.x += p.x; s.y += p.y; s.z += p.z; s.w += p.w;
        }
        float ic = 1.0f / fmaxf((float)(end - beg), 1.0f);
        pooled[tid * 4 + 0] = s.x * ic;
        pooled[tid * 4 + 1] = s.y * ic;
        pooled[tid * 4 + 2] = s.z * ic;
        pooled[tid * 4 + 3] = s.w * ic;
    }
    __syncthreads();
    if (tid < NC) {
        float a = bl[tid];
#pragma unroll 8
        for (int k = 0; k < NF; k++)
            a = fmaf(pooled[k], Wl[k * NC + tid], a);
        out[g * NC + tid] = a;
    }
}

extern "C" void kernel_launch(void* const* d_in, const int* in_sizes, int n_in,
                              void* d_out, int out_size, void* d_ws, size_t ws_size,
                              hipStream_t stream) {
    const float* x  = (const float*)d_in[0];
    const void*  ei = d_in[1];
    const void*  bt = d_in[2];
    const float* W1 = (const float*)d_in[3];
    const float* b1 = (const float*)d_in[4];
    const float* W2 = (const float*)d_in[5];
    const float* b2 = (const float*)d_in[6];
    const float* Wl = (const float*)d_in[7];
    const float* bl = (const float*)d_in[8];

    char* ws = (char*)d_ws;
    int*   coff  = (int*)(ws + 0);
    int*   bbase = (int*)(ws + 40016);
    float* dinv  = (float*)(ws + 41040);
    int*   csrc  = (int*)(ws + 81040);
    float* cw    = (float*)(ws + 2641040);
    float* bufA  = (float*)(ws + 5201040);
    float* bufB  = (float*)(ws + 10321040);
    int*   bh    = (int*)bufA;     // 256 KB scratch, dead before k_gemm #1
    int*   ebuf  = (int*)bufB;     // 2.56 MB scratch, dead before k_gather #1

    k_hist  <<<G1, 256, 0, stream>>>(ei, bh);
    k_bscan <<<1, 1024, 0, stream>>>(bh, bbase);
    k_bucket<<<G1, 256, 0, stream>>>(ei, bh, bbase, ebuf);
    k_csr   <<<NB, 256, 0, stream>>>(ebuf, bbase, coff, dinv, csrc);
    k_cw    <<<(NN + 3) / 4, 256, 0, stream>>>(coff, csrc, dinv, cw);

    k_gemm<<<(NN + TM - 1) / TM, 256, 0, stream>>>(x, W1, bufA, NN);
    k_gather<<<(NN + 3) / 4, 256, 0, stream>>>(bufA, coff, csrc, cw, dinv, b1, bufB);
    k_gemm<<<(NN + TM - 1) / TM, 256, 0, stream>>>(bufB, W2, bufA, NN);
    k_gather<<<(NN + 3) / 4, 256, 0, stream>>>(bufA, coff, csrc, cw, dinv, b2, bufB);

    k_poolfin<<<NG, 256, 0, stream>>>(bufB, bt, Wl, bl, (float*)d_out);
}